// Round 2
// baseline (150.737 us; speedup 1.0000x reference)
//
#include <hip/hip_runtime.h>
#include <cstdint>
#include <cstddef>

#define NB 16
#define NC 256
#define NN 4096
#define ND 256

typedef unsigned short u16;
typedef unsigned int u32;

typedef __attribute__((ext_vector_type(8))) short short8;
typedef __attribute__((ext_vector_type(4))) float f32x4;

__device__ __forceinline__ u16 f2bf(float f) {
  union { float f; u32 u; } v; v.f = f;
  u32 r = v.u + 0x7FFFu + ((v.u >> 16) & 1u);
  return (u16)(r >> 16);
}
__device__ __forceinline__ float bf2f(u16 h) {
  union { u32 u; float f; } v; v.u = ((u32)h) << 16; return v.f;
}

// ---------------------------------------------------------------------------
// Kernel 1: per (b, n-tile of 64) block spanning FULL C=256.
// Register-only cast+transpose: each thread owns a 4c x 4n micro-tile
// (4x float4 loads, coalesced), packs bf16 ushort4 along c in REGISTERS,
// stores xbT[n][c] with 8B stores. No LDS tile, no bank-conflicted scatter.
//   q[n]   = sum_c W[0][c]*x[c][n]      (fp32, LDS reduce, pad-65)
//   m,l    = online-softmax partial     (wave shfl reductions)
//   pacc[c]= sum_n bf16(x[c][n])*e^{q-m} (regs -> LDS reduce, pad-257)
// ---------------------------------------------------------------------------
__global__ __launch_bounds__(256) void k_fuse1(const float* __restrict__ x,
                                               const float* __restrict__ W,
                                               u16* __restrict__ xbT,
                                               float* __restrict__ pm,
                                               float* __restrict__ pl,
                                               float* __restrict__ pacc) {
  __shared__ float qred[16 * 65];                 // 4,160 B
  __shared__ __align__(16) float pv[64];          //   256 B
  __shared__ float pracc[16 * 257];               // 16,448 B
  const int t = threadIdx.x;
  const int b = blockIdx.y, n0 = blockIdx.x * 64;
  const float* xb = x + (size_t)b * NC * NN + n0;
  const int nl = (t & 15) * 4;     // n within tile (4 values)
  const int cq4 = (t >> 4) * 4;    // c base within 64-chunk (4 values)

  ushort4 pk[4][4];                // [i][jn] -> bf16 of c0..c0+3 at n=nl+jn
  float qp0 = 0.f, qp1 = 0.f, qp2 = 0.f, qp3 = 0.f;

#pragma unroll
  for (int i = 0; i < 4; ++i) {
    const int c0 = cq4 + 64 * i;
    const float* xr = xb + (size_t)c0 * NN + nl;
    float4 v0 = *(const float4*)(xr);
    float4 v1 = *(const float4*)(xr + NN);
    float4 v2 = *(const float4*)(xr + 2 * NN);
    float4 v3 = *(const float4*)(xr + 3 * NN);
    const float4 Wq = *(const float4*)(W + c0);
    qp0 += Wq.x * v0.x + Wq.y * v1.x + Wq.z * v2.x + Wq.w * v3.x;
    qp1 += Wq.x * v0.y + Wq.y * v1.y + Wq.z * v2.y + Wq.w * v3.y;
    qp2 += Wq.x * v0.z + Wq.y * v1.z + Wq.z * v2.z + Wq.w * v3.z;
    qp3 += Wq.x * v0.w + Wq.y * v1.w + Wq.z * v2.w + Wq.w * v3.w;
    ushort4 u0 = {f2bf(v0.x), f2bf(v1.x), f2bf(v2.x), f2bf(v3.x)};
    ushort4 u1 = {f2bf(v0.y), f2bf(v1.y), f2bf(v2.y), f2bf(v3.y)};
    ushort4 u2 = {f2bf(v0.z), f2bf(v1.z), f2bf(v2.z), f2bf(v3.z)};
    ushort4 u3 = {f2bf(v0.w), f2bf(v1.w), f2bf(v2.w), f2bf(v3.w)};
    u16* ob = xbT + (size_t)(b * NN + n0 + nl) * NC + c0;
    *(ushort4*)(ob) = u0;
    *(ushort4*)(ob + NC) = u1;
    *(ushort4*)(ob + 2 * NC) = u2;
    *(ushort4*)(ob + 3 * NC) = u3;
    pk[i][0] = u0; pk[i][1] = u1; pk[i][2] = u2; pk[i][3] = u3;
  }

  const int cg = t >> 4;           // 0..15
  qred[cg * 65 + nl + 0] = qp0;
  qred[cg * 65 + nl + 1] = qp1;
  qred[cg * 65 + nl + 2] = qp2;
  qred[cg * 65 + nl + 3] = qp3;
  __syncthreads();

  // every thread recomputes q for n = t&63 (waves redundant, conflict-free)
  float q = 0.f;
#pragma unroll
  for (int k = 0; k < 16; ++k) q += qred[k * 65 + (t & 63)];
  // wave-level max / expsum (all 64 lanes hold the full tile's q)
  float m = q;
#pragma unroll
  for (int off = 1; off < 64; off <<= 1) m = fmaxf(m, __shfl_xor(m, off));
  const float p = __expf(q - m);
  if (t < 64) pv[t] = p;
  float l = p;
#pragma unroll
  for (int off = 1; off < 64; off <<= 1) l += __shfl_xor(l, off);
  __syncthreads();

  // pacc partials from registers
  const float4 pwv = *(const float4*)&pv[nl];
  float sc[4][4];
#pragma unroll
  for (int i = 0; i < 4; ++i) {
    sc[i][0] = sc[i][1] = sc[i][2] = sc[i][3] = 0.f;
#pragma unroll
    for (int jn = 0; jn < 4; ++jn) {
      const ushort4 u = pk[i][jn];
      const float w = (jn == 0) ? pwv.x : (jn == 1) ? pwv.y : (jn == 2) ? pwv.z : pwv.w;
      sc[i][0] += bf2f(u.x) * w;
      sc[i][1] += bf2f(u.y) * w;
      sc[i][2] += bf2f(u.z) * w;
      sc[i][3] += bf2f(u.w) * w;
    }
  }
#pragma unroll
  for (int i = 0; i < 4; ++i) {
#pragma unroll
    for (int j = 0; j < 4; ++j)
      pracc[(t & 15) * 257 + cq4 + 64 * i + j] = sc[i][j];
  }
  __syncthreads();

  float xsp = 0.f;
#pragma unroll
  for (int k = 0; k < 16; ++k) xsp += pracc[k * 257 + t];
  pacc[((size_t)b * 64 + blockIdx.x) * NC + t] = xsp;
  if (t == 0) {
    pm[b * 64 + blockIdx.x] = m;
    pl[b * 64 + blockIdx.x] = l;
  }
}

// ---------------------------------------------------------------------------
// Kernel 2: per batch (16 blocks):
//   M = max_i m_i; L = sum_i e^{m_i-M} l_i; xs[c] = sum_i e^{m_i-M} pacc_i[c] / L
//   ctx[d] = sum_c W[1+d][c] * xs[c];  + Wv bf16 cast folded in.
// ---------------------------------------------------------------------------
__global__ __launch_bounds__(256) void k_combine(const float* __restrict__ W,
                                                 const float* __restrict__ pm,
                                                 const float* __restrict__ pl,
                                                 const float* __restrict__ pacc,
                                                 float* __restrict__ ctx,
                                                 u16* __restrict__ wvb) {
  __shared__ float sm[64], sl[64], sw[64];
  __shared__ float sx[NC];
  const int b = blockIdx.x, t = threadIdx.x;
  if (t < 64) { sm[t] = pm[b * 64 + t]; sl[t] = pl[b * 64 + t]; }
  __syncthreads();
  float M = -3.4e38f;
#pragma unroll 16
  for (int i = 0; i < 64; ++i) M = fmaxf(M, sm[i]);
  if (t < 64) sw[t] = __expf(sm[t] - M);
  __syncthreads();
  float L = 0.f;
#pragma unroll 16
  for (int i = 0; i < 64; ++i) L += sw[i] * sl[i];
  float xsc = 0.f;
#pragma unroll 8
  for (int i = 0; i < 64; ++i) xsc += sw[i] * pacc[((size_t)b * 64 + i) * NC + t];
  sx[t] = xsc / L;
  __syncthreads();
  const float* wk = W + (size_t)(1 + t) * NC;
  float a = 0.f;
#pragma unroll 4
  for (int c = 0; c < NC; ++c) a += wk[c] * sx[c];
  ctx[b * NC + t] = a;
  const float* wv = W + (size_t)(1 + ND) * NC + (size_t)b * 16 * NC;
  u16* wo = wvb + (size_t)b * 16 * NC;
#pragma unroll
  for (int i = 0; i < 16; ++i) wo[i * NC + t] = f2bf(wv[i * NC + t]);
}

// ---------------------------------------------------------------------------
// Kernel 3: out[b][d][n] = relu( (Wv @ x)[d][n] ) * ctx[b][d]
// bf16 MFMA 16x16x32. BM=256 (full D -> xbT read exactly once), BN=128,
// BK=64, 512 threads = 8 waves (4 d x 2 n). XOR-swizzled LDS (16B chunks,
// phys = chunk ^ (row&7)); swizzle applied on the global source per lane so
// global_load_lds keeps a linear LDS destination.
// ---------------------------------------------------------------------------
#define BM 256
#define BN 128
#define BK 64

__global__ __launch_bounds__(512) void k_gemm(const u16* __restrict__ xbT,
                                              const u16* __restrict__ wvb,
                                              const float* __restrict__ ctx,
                                              float* __restrict__ out) {
  __shared__ __align__(16) u16 As[BM * BK];   // 32 KB
  __shared__ __align__(16) u16 Bs[BN * BK];   // 16 KB
  const int t = threadIdx.x;
  const int b = blockIdx.y;
  const int n0 = blockIdx.x * BN;
  const int lane = t & 63, w = t >> 6;
  const int wd = (w >> 1) * 64, wn = (w & 1) * 64;
  const int quad = lane >> 4, l15 = lane & 15;

  f32x4 acc[4][4];
#pragma unroll
  for (int mi = 0; mi < 4; ++mi)
#pragma unroll
    for (int ni = 0; ni < 4; ++ni)
      acc[mi][ni] = (f32x4){0.f, 0.f, 0.f, 0.f};

  const int rstg = t >> 3;                               // 0..63
  const int l8 = ((t & 7) ^ (rstg & 7)) * 8;             // logical u16 offset
  const u16* gA = wvb + (size_t)rstg * NC + l8;
  const u16* gB = xbT + (size_t)(b * NN + n0 + rstg) * NC + l8;
  const int ldst = 8 * t;                                // u16 offset in LDS

  const int pq0 = ((0 * 4 + quad) ^ (l15 & 7)) * 8;
  const int pq1 = ((1 * 4 + quad) ^ (l15 & 7)) * 8;

  for (int kk = 0; kk < NC; kk += BK) {
    __syncthreads();
#pragma unroll
    for (int i = 0; i < 4; ++i)
      __builtin_amdgcn_global_load_lds(
          (const __attribute__((address_space(1))) u32*)(gA + kk + (size_t)(64 * i) * NC),
          (__attribute__((address_space(3))) u32*)(As + 4096 * i + ldst), 16, 0, 0);
#pragma unroll
    for (int i = 0; i < 2; ++i)
      __builtin_amdgcn_global_load_lds(
          (const __attribute__((address_space(1))) u32*)(gB + kk + (size_t)(64 * i) * NC),
          (__attribute__((address_space(3))) u32*)(Bs + 4096 * i + ldst), 16, 0, 0);
    __syncthreads();

#pragma unroll
    for (int kq = 0; kq < 2; ++kq) {
      const int pq = kq ? pq1 : pq0;
      short8 af[4], bfr[4];
#pragma unroll
      for (int mi = 0; mi < 4; ++mi)
        af[mi] = *(const short8*)&As[(wd + mi * 16 + l15) * BK + pq];
#pragma unroll
      for (int ni = 0; ni < 4; ++ni)
        bfr[ni] = *(const short8*)&Bs[(wn + ni * 16 + l15) * BK + pq];
#pragma unroll
      for (int mi = 0; mi < 4; ++mi)
#pragma unroll
        for (int ni = 0; ni < 4; ++ni)
          acc[mi][ni] = __builtin_amdgcn_mfma_f32_16x16x32_bf16(af[mi], bfr[ni],
                                                                acc[mi][ni], 0, 0, 0);
    }
  }

#pragma unroll
  for (int mi = 0; mi < 4; ++mi) {
#pragma unroll
    for (int r = 0; r < 4; ++r) {
      const int d = wd + mi * 16 + quad * 4 + r;
      const float cx = ctx[b * NC + d];
      float* op = out + (size_t)(b * NC + d) * NN + n0 + wn + l15;
#pragma unroll
      for (int ni = 0; ni < 4; ++ni) {
        float v = acc[mi][ni][r];
        op[ni * 16] = fmaxf(v, 0.f) * cx;
      }
    }
  }
}

// ---------------------------------------------------------------------------
extern "C" void kernel_launch(void* const* d_in, const int* in_sizes, int n_in,
                              void* d_out, int out_size, void* d_ws, size_t ws_size,
                              hipStream_t stream) {
  const float* x = (const float*)d_in[0];
  const float* W = (const float*)d_in[1];
  float* out = (float*)d_out;

  char* ws = (char*)d_ws;
  u16* xbT    = (u16*)ws;                                 // 33,554,432 B
  float* pacc = (float*)(ws + 33554432);                  //  1,048,576 B
  float* pm   = (float*)(ws + 34603008);                  //      4,096 B
  float* pl   = (float*)(ws + 34607104);                  //      4,096 B
  float* ctx  = (float*)(ws + 34611200);                  //     16,384 B
  u16* wvb    = (u16*)(ws + 34627584);                    //    131,072 B

  k_fuse1<<<dim3(64, 16), 256, 0, stream>>>(x, W, xbT, pm, pl, pacc);
  k_combine<<<16, 256, 0, stream>>>(W, pm, pl, pacc, ctx, wvb);
  k_gemm<<<dim3(32, 16), 512, 0, stream>>>(xbT, wvb, ctx, out);
}

// Round 3
// 150.545 us; speedup vs baseline: 1.0013x; 1.0013x over previous
//
#include <hip/hip_runtime.h>
#include <cstdint>
#include <cstddef>

#define NB 16
#define NC 256
#define NN 4096
#define ND 256

typedef unsigned short u16;
typedef unsigned int u32;

typedef __attribute__((ext_vector_type(8))) short short8;
typedef __attribute__((ext_vector_type(4))) float f32x4;

__device__ __forceinline__ u16 f2bf(float f) {
  union { float f; u32 u; } v; v.f = f;
  u32 r = v.u + 0x7FFFu + ((v.u >> 16) & 1u);
  return (u16)(r >> 16);
}
__device__ __forceinline__ float bf2f(u16 h) {
  union { u32 u; float f; } v; v.u = ((u32)h) << 16; return v.f;
}

// ---------------------------------------------------------------------------
// Kernel 1: per (b, n-tile of 64) block spanning FULL C=256.
// Thread micro-tile: 8c x 8n. Loads: 16x float4 (2KB/instr coalesced).
// Transpose is pure register renaming -> xbT stores are short8 (16B), a wave
// covers 8 rows x 128B aligned segments. No LDS transpose tile.
//   q[n]   : per-thread 8c partials -> 2-stage conflict-free LDS reduce
//   m, l   : in-wave shfl_xor butterflies over tx bits (all waves identical)
//   pacc[c]: register MACs + in-wave shfl reduce (wave owns 64c x all 64n)
//   + Wv bf16 cast folded into 8 blocks' tail (b==0, blockIdx.x<8)
// ---------------------------------------------------------------------------
__global__ __launch_bounds__(256) void k_fuse1(const float* __restrict__ x,
                                               const float* __restrict__ W,
                                               u16* __restrict__ xbT,
                                               u16* __restrict__ wvb,
                                               float* __restrict__ pm,
                                               float* __restrict__ pl,
                                               float* __restrict__ pacc) {
  __shared__ float qred[32 * 65];   // 8,320 B, bank-conflict-free
  __shared__ float qred2[4 * 65];   // 1,040 B
  const int t = threadIdx.x;
  const int b = blockIdx.y, n0 = blockIdx.x * 64;
  const int tx = t & 7, ty = t >> 3;        // tx: n-group 0..7, ty: c-group 0..31
  const int c0 = ty * 8, nl = tx * 8;
  const float* xb = x + (size_t)b * NC * NN + n0;

  // W[0] weights for this thread's 8 c-rows
  const float4 w0 = *(const float4*)(W + c0);
  const float4 w1 = *(const float4*)(W + c0 + 4);
  const float wq[8] = {w0.x, w0.y, w0.z, w0.w, w1.x, w1.y, w1.z, w1.w};

  short8 pk[8];          // pk[j] = bf16 x[c0..c0+8][nl+j]  (transposed packs)
  float qp[8] = {0.f, 0.f, 0.f, 0.f, 0.f, 0.f, 0.f, 0.f};

#pragma unroll
  for (int r = 0; r < 8; ++r) {
    const float* xr = xb + (size_t)(c0 + r) * NN + nl;
    const float4 va = *(const float4*)(xr);
    const float4 vb = *(const float4*)(xr + 4);
    qp[0] += wq[r] * va.x; qp[1] += wq[r] * va.y;
    qp[2] += wq[r] * va.z; qp[3] += wq[r] * va.w;
    qp[4] += wq[r] * vb.x; qp[5] += wq[r] * vb.y;
    qp[6] += wq[r] * vb.z; qp[7] += wq[r] * vb.w;
    pk[0][r] = (short)f2bf(va.x); pk[1][r] = (short)f2bf(va.y);
    pk[2][r] = (short)f2bf(va.z); pk[3][r] = (short)f2bf(va.w);
    pk[4][r] = (short)f2bf(vb.x); pk[5][r] = (short)f2bf(vb.y);
    pk[6][r] = (short)f2bf(vb.z); pk[7][r] = (short)f2bf(vb.w);
  }

  // transposed store: 8 x short8, wave writes 8 rows x 128B aligned segments
  u16* ob = xbT + (size_t)(b * NN + n0 + nl) * NC + c0;
#pragma unroll
  for (int j = 0; j < 8; ++j)
    *(short8*)(ob + (size_t)j * NC) = pk[j];

  // q reduction stage A: per (c-group, n)
#pragma unroll
  for (int j = 0; j < 8; ++j) qred[ty * 65 + nl + j] = qp[j];
  __syncthreads();
  // stage B: thread -> (g = t>>6, n = t&63) sums its 8 c-groups
  {
    const int n = t & 63, g = t >> 6;
    float s = 0.f;
#pragma unroll
    for (int k = 0; k < 8; ++k) s += qred[(g * 8 + k) * 65 + n];
    qred2[g * 65 + n] = s;
  }
  __syncthreads();

  // final q for this thread's 8 n (identical across ty / waves)
  float q[8];
#pragma unroll
  for (int j = 0; j < 8; ++j)
    q[j] = qred2[0 * 65 + nl + j] + qred2[1 * 65 + nl + j] +
           qred2[2 * 65 + nl + j] + qred2[3 * 65 + nl + j];

  float m = q[0];
#pragma unroll
  for (int j = 1; j < 8; ++j) m = fmaxf(m, q[j]);
#pragma unroll
  for (int off = 1; off < 8; off <<= 1) m = fmaxf(m, __shfl_xor(m, off));

  float p[8]; float l = 0.f;
#pragma unroll
  for (int j = 0; j < 8; ++j) { p[j] = __expf(q[j] - m); l += p[j]; }
#pragma unroll
  for (int off = 1; off < 8; off <<= 1) l += __shfl_xor(l, off);

  // pacc: sc[r] = sum_j bf16(x[c0+r][nl+j]) * p[j]; reduce over tx in-wave
  float sc[8];
#pragma unroll
  for (int r = 0; r < 8; ++r) {
    float s = 0.f;
#pragma unroll
    for (int j = 0; j < 8; ++j) s += bf2f((u16)pk[j][r]) * p[j];
    sc[r] = s;
  }
#pragma unroll
  for (int off = 1; off < 8; off <<= 1) {
#pragma unroll
    for (int r = 0; r < 8; ++r) sc[r] += __shfl_xor(sc[r], off);
  }
  if (tx == 0) {
    float* pp = pacc + ((size_t)b * 64 + blockIdx.x) * NC + c0;
#pragma unroll
    for (int r = 0; r < 8; ++r) pp[r] = sc[r];
  }
  if (t == 0) {
    pm[b * 64 + blockIdx.x] = m;
    pl[b * 64 + blockIdx.x] = l;
  }

  // Wv bf16 cast, folded into 8 blocks (coalesced 4KB per instruction)
  if (b == 0 && blockIdx.x < 8) {
    const float* wv = W + (size_t)(1 + ND) * NC;
    const int base = blockIdx.x * 8192;
#pragma unroll
    for (int i = 0; i < 8; ++i) {
      const int idx = base + i * 1024 + t * 4;
      const float4 v = *(const float4*)(wv + idx);
      ushort4 o = {f2bf(v.x), f2bf(v.y), f2bf(v.z), f2bf(v.w)};
      *(ushort4*)(wvb + idx) = o;
    }
  }
}

// ---------------------------------------------------------------------------
// Kernel 2: per batch (16 blocks):
//   M = max_i m_i; L = sum_i e^{m_i-M} l_i; xs[c] = sum_i e^{m_i-M} pacc_i[c] / L
//   ctx[d] = sum_c W[1+d][c] * xs[c]   (float4 W-k loads)
// ---------------------------------------------------------------------------
__global__ __launch_bounds__(256) void k_combine(const float* __restrict__ W,
                                                 const float* __restrict__ pm,
                                                 const float* __restrict__ pl,
                                                 const float* __restrict__ pacc,
                                                 float* __restrict__ ctx) {
  __shared__ float sm[64], sl[64], sw[64];
  __shared__ __align__(16) float sx[NC];
  const int b = blockIdx.x, t = threadIdx.x;
  if (t < 64) { sm[t] = pm[b * 64 + t]; sl[t] = pl[b * 64 + t]; }
  __syncthreads();
  float M = -3.4e38f;
#pragma unroll 16
  for (int i = 0; i < 64; ++i) M = fmaxf(M, sm[i]);
  if (t < 64) sw[t] = __expf(sm[t] - M);
  __syncthreads();
  float L = 0.f;
#pragma unroll 16
  for (int i = 0; i < 64; ++i) L += sw[i] * sl[i];
  float xsc = 0.f;
#pragma unroll 8
  for (int i = 0; i < 64; ++i) xsc += sw[i] * pacc[((size_t)b * 64 + i) * NC + t];
  sx[t] = xsc / L;
  __syncthreads();
  const float* wk = W + (size_t)(1 + t) * NC;
  float a = 0.f;
#pragma unroll 4
  for (int c4 = 0; c4 < 64; ++c4) {
    const float4 w4 = *(const float4*)(wk + c4 * 4);
    const float4 s4 = *(const float4*)&sx[c4 * 4];
    a += w4.x * s4.x + w4.y * s4.y + w4.z * s4.z + w4.w * s4.w;
  }
  ctx[b * NC + t] = a;
}

// ---------------------------------------------------------------------------
// Kernel 3: out[b][d][n] = relu( (Wv @ x)[d][n] ) * ctx[b][d]
// bf16 MFMA 16x16x32. BM=256 (full D -> xbT read exactly once), BN=128,
// BK=64, 512 threads = 8 waves (4 d x 2 n). XOR-swizzled LDS (16B chunks,
// phys = chunk ^ (row&7)); swizzle applied on the global source per lane so
// global_load_lds keeps a linear LDS destination.
// ---------------------------------------------------------------------------
#define BM 256
#define BN 128
#define BK 64

__global__ __launch_bounds__(512) void k_gemm(const u16* __restrict__ xbT,
                                              const u16* __restrict__ wvb,
                                              const float* __restrict__ ctx,
                                              float* __restrict__ out) {
  __shared__ __align__(16) u16 As[BM * BK];   // 32 KB
  __shared__ __align__(16) u16 Bs[BN * BK];   // 16 KB
  const int t = threadIdx.x;
  const int b = blockIdx.y;
  const int n0 = blockIdx.x * BN;
  const int lane = t & 63, w = t >> 6;
  const int wd = (w >> 1) * 64, wn = (w & 1) * 64;
  const int quad = lane >> 4, l15 = lane & 15;

  f32x4 acc[4][4];
#pragma unroll
  for (int mi = 0; mi < 4; ++mi)
#pragma unroll
    for (int ni = 0; ni < 4; ++ni)
      acc[mi][ni] = (f32x4){0.f, 0.f, 0.f, 0.f};

  const int rstg = t >> 3;                               // 0..63
  const int l8 = ((t & 7) ^ (rstg & 7)) * 8;             // logical u16 offset
  const u16* gA = wvb + (size_t)rstg * NC + l8;
  const u16* gB = xbT + (size_t)(b * NN + n0 + rstg) * NC + l8;
  const int ldst = 8 * t;                                // u16 offset in LDS

  const int pq0 = ((0 * 4 + quad) ^ (l15 & 7)) * 8;
  const int pq1 = ((1 * 4 + quad) ^ (l15 & 7)) * 8;

  for (int kk = 0; kk < NC; kk += BK) {
    __syncthreads();
#pragma unroll
    for (int i = 0; i < 4; ++i)
      __builtin_amdgcn_global_load_lds(
          (const __attribute__((address_space(1))) u32*)(gA + kk + (size_t)(64 * i) * NC),
          (__attribute__((address_space(3))) u32*)(As + 4096 * i + ldst), 16, 0, 0);
#pragma unroll
    for (int i = 0; i < 2; ++i)
      __builtin_amdgcn_global_load_lds(
          (const __attribute__((address_space(1))) u32*)(gB + kk + (size_t)(64 * i) * NC),
          (__attribute__((address_space(3))) u32*)(Bs + 4096 * i + ldst), 16, 0, 0);
    __syncthreads();

#pragma unroll
    for (int kq = 0; kq < 2; ++kq) {
      const int pq = kq ? pq1 : pq0;
      short8 af[4], bfr[4];
#pragma unroll
      for (int mi = 0; mi < 4; ++mi)
        af[mi] = *(const short8*)&As[(wd + mi * 16 + l15) * BK + pq];
#pragma unroll
      for (int ni = 0; ni < 4; ++ni)
        bfr[ni] = *(const short8*)&Bs[(wn + ni * 16 + l15) * BK + pq];
#pragma unroll
      for (int mi = 0; mi < 4; ++mi)
#pragma unroll
        for (int ni = 0; ni < 4; ++ni)
          acc[mi][ni] = __builtin_amdgcn_mfma_f32_16x16x32_bf16(af[mi], bfr[ni],
                                                                acc[mi][ni], 0, 0, 0);
    }
  }

#pragma unroll
  for (int mi = 0; mi < 4; ++mi) {
#pragma unroll
    for (int r = 0; r < 4; ++r) {
      const int d = wd + mi * 16 + quad * 4 + r;
      const float cx = ctx[b * NC + d];
      float* op = out + (size_t)(b * NC + d) * NN + n0 + wn + l15;
#pragma unroll
      for (int ni = 0; ni < 4; ++ni) {
        float v = acc[mi][ni][r];
        op[ni * 16] = fmaxf(v, 0.f) * cx;
      }
    }
  }
}

// ---------------------------------------------------------------------------
extern "C" void kernel_launch(void* const* d_in, const int* in_sizes, int n_in,
                              void* d_out, int out_size, void* d_ws, size_t ws_size,
                              hipStream_t stream) {
  const float* x = (const float*)d_in[0];
  const float* W = (const float*)d_in[1];
  float* out = (float*)d_out;

  char* ws = (char*)d_ws;
  u16* xbT    = (u16*)ws;                                 // 33,554,432 B
  float* pacc = (float*)(ws + 33554432);                  //  1,048,576 B
  float* pm   = (float*)(ws + 34603008);                  //      4,096 B
  float* pl   = (float*)(ws + 34607104);                  //      4,096 B
  float* ctx  = (float*)(ws + 34611200);                  //     16,384 B
  u16* wvb    = (u16*)(ws + 34627584);                    //    131,072 B

  k_fuse1<<<dim3(64, 16), 256, 0, stream>>>(x, W, xbT, wvb, pm, pl, pacc);
  k_combine<<<16, 256, 0, stream>>>(W, pm, pl, pacc, ctx);
  k_gemm<<<dim3(32, 16), 512, 0, stream>>>(xbT, wvb, ctx, out);
}